// Round 12
// baseline (76.037 us; speedup 1.0000x reference)
//
#include <hip/hip_runtime.h>
#include <math.h>

#define LOG2E 1.4426950408889634f
#define LN2   0.6931471805599453f

typedef float v2f __attribute__((ext_vector_type(2)));

__device__ __forceinline__ float fast_exp2(float x) {
    return __builtin_amdgcn_exp2f(x);
}

// Packed fp32 FMA (VOP3P) — proven equal-or-better vs scalar (R10 A/B).
__device__ __forceinline__ v2f pk_fma(v2f a, v2f b, v2f c) {
    v2f d;
    asm("v_pk_fma_f32 %0, %1, %2, %3" : "=v"(d) : "v"(a), "v"(b), "v"(c));
    return d;
}
// Packed fp32 add (VOP3P): halves the accumulate issue slots.
__device__ __forceinline__ v2f pk_add(v2f a, v2f b) {
    v2f d;
    asm("v_pk_add_f32 %0, %1, %2" : "=v"(d) : "v"(a), "v"(b));
    return d;
}

// ---------------------------------------------------------------------------
// R8 skeleton EXACTLY (best known: 19.2 us), plus two proven-safe trims:
//   - v_pk_add_f32 accumulation (16 scalar adds -> 8 packed)
//   - hoisted wave-uniform sample pointer
// Sample loop stays "#pragma unroll 2" — R11 showed full unroll makes the
// compiler rematerialize coefficients from LDS (VGPR 64, scratch, 4x slower).
// Block = 512 threads (8 waves), 128 samples/block, 512 blocks (2/CU).
// ---------------------------------------------------------------------------
__global__ __launch_bounds__(512, 4) void gm_fused(
        const float* __restrict__ sample,   // [N,2]
        const float* __restrict__ mu,       // [M,2]
        const float* __restrict__ A,        // [M,2,2]
        const float* __restrict__ w,        // [M,1]
        float* __restrict__ out) {          // [N,1]
    __shared__ __align__(16) v2f  COEF2[6][512];   // 24 KB
    __shared__ __align__(16) float RED[128][68];   // 34.8 KB, 16B-aligned rows
    __shared__ float PART[128][5];                 // 2.6 KB
    __shared__ float red8[8];

    const int tid  = threadIdx.x;
    const int lane = tid & 63;
    const int wid  = tid >> 6;              // 0..7

    // ================= Phase 1: coefficient prep ==========================
    const float2 wv = ((const float2*)w)[tid];      // comps 2t, 2t+1

    float v = fmaxf(wv.x, wv.y);
    #pragma unroll
    for (int o = 32; o; o >>= 1) v = fmaxf(v, __shfl_xor(v, o));
    if (lane == 0) red8[wid] = v;
    __syncthreads();
    float wmax = red8[0];
    #pragma unroll
    for (int k = 1; k < 8; k++) wmax = fmaxf(wmax, red8[k]);
    __syncthreads();

    v = expf(wv.x - wmax) + expf(wv.y - wmax);
    #pragma unroll
    for (int o = 32; o; o >>= 1) v += __shfl_xor(v, o);
    if (lane == 0) red8[wid] = v;
    __syncthreads();
    float sumew = 0.f;
    #pragma unroll
    for (int k = 0; k < 8; k++) sumew += red8[k];
    const float lse = wmax + logf(sumew);
    __syncthreads();                                 // red8 reused below

    float lw2[2], G00[2], G2[2], G11[2], MX[2], MY[2];
    const float wj[2] = {wv.x, wv.y};
    #pragma unroll
    for (int k = 0; k < 2; k++) {
        const int j = 2 * tid + k;
        const float4 a = ((const float4*)A)[j];
        const float g00 = 0.5f * (a.x*a.x + a.y*a.y);
        const float g01 = 0.5f * (a.x*a.z + a.y*a.w);
        const float g11 = 0.5f * (a.z*a.z + a.w*a.w);
        const float det = g00*g11 - g01*g01;
        lw2[k] = ((wj[k] - lse) + 0.5f * logf(det)) * LOG2E;
        G00[k] = g00 * LOG2E;
        G2[k]  = 2.f * g01 * LOG2E;
        G11[k] = g11 * LOG2E;
        const float2 m = ((const float2*)mu)[j];
        MX[k] = m.x; MY[k] = m.y;
    }

    v = fmaxf(lw2[0], lw2[1]);
    #pragma unroll
    for (int o = 32; o; o >>= 1) v = fmaxf(v, __shfl_xor(v, o));
    if (lane == 0) red8[wid] = v;
    __syncthreads();
    float Lmax = red8[0];
    #pragma unroll
    for (int k = 1; k < 8; k++) Lmax = fmaxf(Lmax, red8[k]);

    {
        v2f c0v, c1v, c2v, d0v, d1v, d2v;
        #pragma unroll
        for (int k = 0; k < 2; k++) {
            const float mx = MX[k], my = MY[k];
            c0v[k] = lw2[k] - (G00[k]*mx*mx + G2[k]*mx*my + G11[k]*my*my) - Lmax;
            c1v[k] = 2.f*G00[k]*mx + G2[k]*my;
            c2v[k] = G2[k]*mx + 2.f*G11[k]*my;
            d0v[k] = -G00[k];
            d1v[k] = -G2[k];
            d2v[k] = -G11[k];
        }
        COEF2[0][tid] = c0v;  COEF2[1][tid] = c1v;  COEF2[2][tid] = c2v;
        COEF2[3][tid] = d0v;  COEF2[4][tid] = d1v;  COEF2[5][tid] = d2v;
    }
    __syncthreads();

    // ========= Phase 2: 16 comps/lane -> 8 packed pairs in VGPRs ==========
    // pair p = 64k + lane -> components (2p, 2p+1); one ds_read_b64 each.
    v2f C0[8], C1[8], C2[8], D0[8], D1[8], D2[8];
    #pragma unroll
    for (int k = 0; k < 8; k++) {
        const int p = (k << 6) + lane;
        C0[k] = COEF2[0][p];  C1[k] = COEF2[1][p];  C2[k] = COEF2[2][p];
        D0[k] = COEF2[3][p];  D1[k] = COEF2[4][p];  D2[k] = COEF2[5][p];
    }

    // ================= Phase 3: hot loop, 16 uniform samples ==============
    const int ls0 = wid * 16;
    const int sbu = __builtin_amdgcn_readfirstlane(blockIdx.x * 128 + ls0);
    const float2* sp = (const float2*)sample + sbu;

    #pragma unroll 2
    for (int s = 0; s < 16; ++s) {
        const float2 xy = sp[s];                      // uniform s_load
        const v2f Xv = {xy.x, xy.x}, Yv = {xy.y, xy.y};

        v2f acc01 = {0.f, 0.f}, acc23 = {0.f, 0.f};
        #pragma unroll
        for (int k = 0; k < 8; k++) {
            // t = c0 + x*(c1 + d0*x + d1*y) + y*(c2 + d2*y)
            v2f i1 = pk_fma(D0[k], Xv, C1[k]);
            i1     = pk_fma(D1[k], Yv, i1);
            v2f i2 = pk_fma(D2[k], Yv, C2[k]);
            v2f t  = pk_fma(i1, Xv, C0[k]);
            t      = pk_fma(i2, Yv, t);
            v2f e;
            e.x = fast_exp2(t.x);
            e.y = fast_exp2(t.y);
            if (k & 1) acc23 = pk_add(acc23, e);
            else       acc01 = pk_add(acc01, e);
        }
        const v2f accs = pk_add(acc01, acc23);
        RED[ls0 + s][lane] = accs.x + accs.y;
    }
    __syncthreads();

    // ---- stage 1: 4 partials per sample (float4 LDS reads, 2-way max) ----
    {
        const int r = tid >> 2, c = tid & 3;
        const float4* row = (const float4*)&RED[r][c * 16];
        const float4 q0 = row[0], q1 = row[1], q2 = row[2], q3 = row[3];
        PART[r][c] = ((q0.x + q0.y) + (q0.z + q0.w))
                   + ((q1.x + q1.y) + (q1.z + q1.w))
                   + ((q2.x + q2.y) + (q2.z + q2.w))
                   + ((q3.x + q3.y) + (q3.z + q3.w));
    }
    __syncthreads();

    // ---- stage 2: finish 128 samples ----
    if (tid < 128) {
        const float st = (PART[tid][0] + PART[tid][1])
                       + (PART[tid][2] + PART[tid][3]);
        const int si = blockIdx.x * 128 + tid;
        float ll;
        if (st >= 1e-30f) {
            ll = LN2 * (Lmax + log2f(st));
        } else {
            // Rare underflow: re-anchored two-pass over all M from LDS COEF2.
            const float2 xy = ((const float2*)sample)[si];
            const float x = xy.x, y = xy.y;
            float m = -3e38f;
            for (int p = 0; p < 512; p++) {
                const v2f c0 = COEF2[0][p], c1 = COEF2[1][p], c2 = COEF2[2][p];
                const v2f d0 = COEF2[3][p], d1 = COEF2[4][p], d2 = COEF2[5][p];
                #pragma unroll
                for (int h = 0; h < 2; h++) {
                    float i1 = fmaf(d0[h], x, c1[h]);
                    i1 = fmaf(d1[h], y, i1);
                    float i2 = fmaf(d2[h], y, c2[h]);
                    float t = fmaf(i1, x, c0[h]);
                    t = fmaf(i2, y, t);
                    m = fmaxf(m, t);
                }
            }
            float ss = 0.f;
            for (int p = 0; p < 512; p++) {
                const v2f c0 = COEF2[0][p], c1 = COEF2[1][p], c2 = COEF2[2][p];
                const v2f d0 = COEF2[3][p], d1 = COEF2[4][p], d2 = COEF2[5][p];
                #pragma unroll
                for (int h = 0; h < 2; h++) {
                    float i1 = fmaf(d0[h], x, c1[h]);
                    i1 = fmaf(d1[h], y, i1);
                    float i2 = fmaf(d2[h], y, c2[h]);
                    float t = fmaf(i1, x, c0[h]);
                    t = fmaf(i2, y, t);
                    ss += fast_exp2(t - m);
                }
            }
            ll = LN2 * (Lmax + m + log2f(ss));
        }
        out[si] = ll;
    }
}

extern "C" void kernel_launch(void* const* d_in, const int* in_sizes, int n_in,
                              void* d_out, int out_size, void* d_ws, size_t ws_size,
                              hipStream_t stream) {
    const float* sample = (const float*)d_in[0];   // [N,2]
    const float* mu     = (const float*)d_in[1];   // [M,2]
    const float* A      = (const float*)d_in[2];   // [M,2,2]
    const float* w      = (const float*)d_in[3];   // [M,1]
    float* out = (float*)d_out;

    const int N = in_sizes[0] / 2;                 // 65536
    // M fixed at 1024 (register/LDS layouts sized statically).

    gm_fused<<<N / 128, 512, 0, stream>>>(sample, mu, A, w, out);
}

// Round 13
// 19.251 us; speedup vs baseline: 3.9497x; 3.9497x over previous
//
#include <hip/hip_runtime.h>
#include <math.h>

#define LOG2E 1.4426950408889634f
#define LN2   0.6931471805599453f

typedef float v2f __attribute__((ext_vector_type(2)));

__device__ __forceinline__ float fast_exp2(float x) {
    return __builtin_amdgcn_exp2f(x);
}

// Guaranteed packed fp32 FMA (CDNA2+ VOP3P). The compiler does not reliably
// pack __builtin_elementwise_fma on v2f; this pins it.
__device__ __forceinline__ v2f pk_fma(v2f a, v2f b, v2f c) {
    v2f d;
    asm("v_pk_fma_f32 %0, %1, %2, %3" : "=v"(d) : "v"(a), "v"(b), "v"(c));
    return d;
}

// ---------------------------------------------------------------------------
// Byte-exact reproduction of the Round-8 kernel (measured 19.23 us) —
// the best-known configuration. Scalar accumulators (s0..s3) keep the
// pair-constrained VGPR demand under the 128 cap; R11/R12 showed that adding
// packed-asm accumulators tips the allocator into LDS rematerialization
// (VGPR 60, 4x slowdown).
// Block = 512 threads (8 waves), 128 samples/block, 512 blocks (2/CU).
// ---------------------------------------------------------------------------
__global__ __launch_bounds__(512, 4) void gm_fused(
        const float* __restrict__ sample,   // [N,2]
        const float* __restrict__ mu,       // [M,2]
        const float* __restrict__ A,        // [M,2,2]
        const float* __restrict__ w,        // [M,1]
        float* __restrict__ out) {          // [N,1]
    __shared__ v2f  COEF2[6][512];          // 24 KB
    __shared__ float RED[128][65];          // 33.3 KB
    __shared__ float PART[128][5];          // 2.6 KB
    __shared__ float red8[8];

    const int tid  = threadIdx.x;
    const int lane = tid & 63;
    const int wid  = tid >> 6;              // 0..7

    // ================= Phase 1: coefficient prep ==========================
    const float2 wv = ((const float2*)w)[tid];      // comps 2t, 2t+1

    float v = fmaxf(wv.x, wv.y);
    #pragma unroll
    for (int o = 32; o; o >>= 1) v = fmaxf(v, __shfl_xor(v, o));
    if (lane == 0) red8[wid] = v;
    __syncthreads();
    float wmax = red8[0];
    #pragma unroll
    for (int k = 1; k < 8; k++) wmax = fmaxf(wmax, red8[k]);
    __syncthreads();

    v = expf(wv.x - wmax) + expf(wv.y - wmax);
    #pragma unroll
    for (int o = 32; o; o >>= 1) v += __shfl_xor(v, o);
    if (lane == 0) red8[wid] = v;
    __syncthreads();
    float sumew = 0.f;
    #pragma unroll
    for (int k = 0; k < 8; k++) sumew += red8[k];
    const float lse = wmax + logf(sumew);
    __syncthreads();                                 // red8 reused below

    float lw2[2], G00[2], G2[2], G11[2], MX[2], MY[2];
    const float wj[2] = {wv.x, wv.y};
    #pragma unroll
    for (int k = 0; k < 2; k++) {
        const int j = 2 * tid + k;
        const float4 a = ((const float4*)A)[j];
        const float g00 = 0.5f * (a.x*a.x + a.y*a.y);
        const float g01 = 0.5f * (a.x*a.z + a.y*a.w);
        const float g11 = 0.5f * (a.z*a.z + a.w*a.w);
        const float det = g00*g11 - g01*g01;
        lw2[k] = ((wj[k] - lse) + 0.5f * logf(det)) * LOG2E;
        G00[k] = g00 * LOG2E;
        G2[k]  = 2.f * g01 * LOG2E;
        G11[k] = g11 * LOG2E;
        const float2 m = ((const float2*)mu)[j];
        MX[k] = m.x; MY[k] = m.y;
    }

    v = fmaxf(lw2[0], lw2[1]);
    #pragma unroll
    for (int o = 32; o; o >>= 1) v = fmaxf(v, __shfl_xor(v, o));
    if (lane == 0) red8[wid] = v;
    __syncthreads();
    float Lmax = red8[0];
    #pragma unroll
    for (int k = 1; k < 8; k++) Lmax = fmaxf(Lmax, red8[k]);

    {
        v2f c0v, c1v, c2v, d0v, d1v, d2v;
        #pragma unroll
        for (int k = 0; k < 2; k++) {
            const float mx = MX[k], my = MY[k];
            c0v[k] = lw2[k] - (G00[k]*mx*mx + G2[k]*mx*my + G11[k]*my*my) - Lmax;
            c1v[k] = 2.f*G00[k]*mx + G2[k]*my;
            c2v[k] = G2[k]*mx + 2.f*G11[k]*my;
            d0v[k] = -G00[k];
            d1v[k] = -G2[k];
            d2v[k] = -G11[k];
        }
        COEF2[0][tid] = c0v;  COEF2[1][tid] = c1v;  COEF2[2][tid] = c2v;
        COEF2[3][tid] = d0v;  COEF2[4][tid] = d1v;  COEF2[5][tid] = d2v;
    }
    __syncthreads();

    // ========= Phase 2: 16 comps/lane -> 8 packed pairs in VGPRs ==========
    // pair p = 64k + lane  -> components (2p, 2p+1); one ds_read_b64 each.
    v2f C0[8], C1[8], C2[8], D0[8], D1[8], D2[8];
    #pragma unroll
    for (int k = 0; k < 8; k++) {
        const int p = (k << 6) + lane;
        C0[k] = COEF2[0][p];  C1[k] = COEF2[1][p];  C2[k] = COEF2[2][p];
        D0[k] = COEF2[3][p];  D1[k] = COEF2[4][p];  D2[k] = COEF2[5][p];
    }

    // ================= Phase 3: hot loop, 16 uniform samples ==============
    const int ls0 = wid * 16;
    const int sbu = __builtin_amdgcn_readfirstlane(blockIdx.x * 128 + ls0);

    #pragma unroll 2
    for (int s = 0; s < 16; ++s) {
        const float2 xy = ((const float2*)sample)[sbu + s];    // s_load
        const v2f Xv = {xy.x, xy.x}, Yv = {xy.y, xy.y};

        float s0 = 0.f, s1 = 0.f, s2 = 0.f, s3 = 0.f;
        #pragma unroll
        for (int k = 0; k < 8; k += 2) {
            // t = c0 + x*(c1 + d0*x + d1*y) + y*(c2 + d2*y)
            v2f i1a = pk_fma(D0[k],   Xv, C1[k]);
            v2f i1b = pk_fma(D0[k+1], Xv, C1[k+1]);
            i1a = pk_fma(D1[k],   Yv, i1a);
            i1b = pk_fma(D1[k+1], Yv, i1b);
            v2f i2a = pk_fma(D2[k],   Yv, C2[k]);
            v2f i2b = pk_fma(D2[k+1], Yv, C2[k+1]);
            v2f ta = pk_fma(i1a, Xv, C0[k]);
            v2f tb = pk_fma(i1b, Xv, C0[k+1]);
            ta = pk_fma(i2a, Yv, ta);
            tb = pk_fma(i2b, Yv, tb);
            s0 += fast_exp2(ta.x);
            s1 += fast_exp2(ta.y);
            s2 += fast_exp2(tb.x);
            s3 += fast_exp2(tb.y);
        }
        RED[ls0 + s][lane] = (s0 + s1) + (s2 + s3);
    }
    __syncthreads();

    // ---- stage 1: 4 partials per sample (2-way LDS access, free) ----
    {
        const int r = tid >> 2, c = tid & 3;
        const float* row = &RED[r][c * 16];
        float p = 0.f;
        #pragma unroll
        for (int i = 0; i < 16; i++) p += row[i];
        PART[r][c] = p;
    }
    __syncthreads();

    // ---- stage 2: finish 128 samples ----
    if (tid < 128) {
        const float st = (PART[tid][0] + PART[tid][1])
                       + (PART[tid][2] + PART[tid][3]);
        const int si = blockIdx.x * 128 + tid;
        float ll;
        if (st >= 1e-30f) {
            ll = LN2 * (Lmax + log2f(st));
        } else {
            // Rare underflow: re-anchored two-pass over all M from LDS COEF2.
            const float2 xy = ((const float2*)sample)[si];
            const float x = xy.x, y = xy.y;
            float m = -3e38f;
            for (int p = 0; p < 512; p++) {
                const v2f c0 = COEF2[0][p], c1 = COEF2[1][p], c2 = COEF2[2][p];
                const v2f d0 = COEF2[3][p], d1 = COEF2[4][p], d2 = COEF2[5][p];
                #pragma unroll
                for (int h = 0; h < 2; h++) {
                    float i1 = fmaf(d0[h], x, c1[h]);
                    i1 = fmaf(d1[h], y, i1);
                    float i2 = fmaf(d2[h], y, c2[h]);
                    float t = fmaf(i1, x, c0[h]);
                    t = fmaf(i2, y, t);
                    m = fmaxf(m, t);
                }
            }
            float ss = 0.f;
            for (int p = 0; p < 512; p++) {
                const v2f c0 = COEF2[0][p], c1 = COEF2[1][p], c2 = COEF2[2][p];
                const v2f d0 = COEF2[3][p], d1 = COEF2[4][p], d2 = COEF2[5][p];
                #pragma unroll
                for (int h = 0; h < 2; h++) {
                    float i1 = fmaf(d0[h], x, c1[h]);
                    i1 = fmaf(d1[h], y, i1);
                    float i2 = fmaf(d2[h], y, c2[h]);
                    float t = fmaf(i1, x, c0[h]);
                    t = fmaf(i2, y, t);
                    ss += fast_exp2(t - m);
                }
            }
            ll = LN2 * (Lmax + m + log2f(ss));
        }
        out[si] = ll;
    }
}

extern "C" void kernel_launch(void* const* d_in, const int* in_sizes, int n_in,
                              void* d_out, int out_size, void* d_ws, size_t ws_size,
                              hipStream_t stream) {
    const float* sample = (const float*)d_in[0];   // [N,2]
    const float* mu     = (const float*)d_in[1];   // [M,2]
    const float* A      = (const float*)d_in[2];   // [M,2,2]
    const float* w      = (const float*)d_in[3];   // [M,1]
    float* out = (float*)d_out;

    const int N = in_sizes[0] / 2;                 // 65536
    // M fixed at 1024 (register/LDS layouts sized statically).

    gm_fused<<<N / 128, 512, 0, stream>>>(sample, mu, A, w, out);
}